// Round 11
// baseline (100.989 us; speedup 1.0000x reference)
//
#include <hip/hip_runtime.h>

// sPLL — final kernel. Arithmetic identified by R8-R10 bisection to match
// the harness's np reference bit-for-bit on all 65.5M spike outputs:
//   * divides -> reciprocal multiplies: *100.0f  and  *999.99993896484375f
//   * drive  = fma(Il+steady, r_c, (-V)*100.0f)   [second-operand FMA]
//   * V      = fma(dt, drive, V)                  [accumulate FMA]
//   * Il / itrg leak updates NOT contracted (mul then add, barriered)
//   * all select/mask algebra exact ({0,1} gates, small-int counters)
// One thread per (b,n) cell; state in registers; 2 coalesced f32 stores/step.
static constexpr int T  = 500;
static constexpr int BS = 256;
static constexpr int N  = 256;

#define FPBAR(x) asm("" : "+v"(x))

__global__ __launch_bounds__(256, 1) void spll_kernel(
    const float* __restrict__ inp,      // (T, BS)
    const float* __restrict__ current,  // (N,)
    float* __restrict__ out)            // (2, T, BS, N)
{
#pragma clang fp contract(off)
    const int b = blockIdx.x;
    const int n = threadIdx.x;

    __shared__ float s_inp[T];
    for (int i = threadIdx.x; i < T; i += blockDim.x)
        s_inp[i] = inp[i * BS + b];
    __syncthreads();

    const float RC = 999.99993896484375f;   // f32(1/f32(0.001))
    const float steady = current[n];

    float Vl = 1.0f, Il = 0.0f, crl = 0.0f;
    float Vt = 0.0f, itrg = 0.0f, ifac = 0.0f, crt = 0.0f;
    float spk_prev = 0.0f;

    float* p0 = out + (size_t)b * N + n;
    float* p1 = p0 + (size_t)T * BS * N;
    const size_t step = (size_t)BS * N;

    for (int t = 0; t < T; ++t) {
        const float x = s_inp[t];

        // ---- LIF ----
        // Il = Il*0.8 + 1e-3*spk_prev   (NOT contracted)
        float u0 = Il * 0.8f;                    FPBAR(u0);
        float u1 = 1e-3f * spk_prev;             FPBAR(u1);   // exact
        Il = u0 + u1;                            FPBAR(Il);
        // Vl = fma(1e-3, fma(Il+steady, RC, (-Vl)*100), Vl)
        float u2 = -Vl;                          FPBAR(u2);
        float u3 = u2 * 100.0f;                  FPBAR(u3);
        float u4 = Il + steady;                  FPBAR(u4);
        float u6 = __builtin_fmaf(u4, RC, u3);   FPBAR(u6);
        Vl = __builtin_fmaf(1e-3f, u6, Vl);      FPBAR(Vl);
        float dvl = Vl - 1.0f;                   FPBAR(dvl);
        float spk_l = (dvl > 0.0f) ? 1.0f : 0.0f;
        float ns = 1.0f - spk_l;                             // exact
        float u8 = crl - 1.0f;                               // exact
        crl = 2.0f * spk_l + ns * u8;            FPBAR(crl); // exact
        float g1 = (crl <= 0.0f) ? 1.0f : 0.0f;
        float u9  = ns * Vl;                                 // exact select
        float u10 = u9 * g1;                                 // exact select
        Vl = u10 + spk_l * 0.0f;                 FPBAR(Vl);

        // ---- TDE ----
        float u11 = ifac * ns;                               // exact select
        float u12 = spk_l * 1.0f;                            // exact
        float u13 = u12 + u11;                   FPBAR(u13); // exact
        ifac = u13 * 0.8f;                       FPBAR(ifac);
        // itrg = itrg*0.9 + pulse   (NOT contracted)
        float w0 = itrg * 0.9f;                  FPBAR(w0);
        float m1 = (ifac > 0.1f) ? 1.0f : 0.0f;
        float u14 = x * 2.0f;                                // exact
        float u15 = u14 * ifac;                  FPBAR(u15);
        float u16 = u15 * m1;                                // exact select
        itrg = w0 + u16;                         FPBAR(itrg);
        // Vt = fma(1e-3, fma(itrg, RC, (-Vt)*100), Vt)
        float u17 = -Vt;                         FPBAR(u17);
        float u18 = u17 * 100.0f;                FPBAR(u18);
        float u20 = __builtin_fmaf(itrg, RC, u18); FPBAR(u20);
        Vt = __builtin_fmaf(1e-3f, u20, Vt);     FPBAR(Vt);
        float dvt = Vt - 1.0f;                   FPBAR(dvt);
        float spk_t = (dvt > 0.0f) ? 1.0f : 0.0f;
        float nst = 1.0f - spk_t;
        float u22 = crt - 1.0f;
        crt = 2.0f * spk_t + nst * u22;          FPBAR(crt);
        float g2 = (crt <= 0.0f) ? 1.0f : 0.0f;
        float u23 = nst * Vt;
        float u24 = u23 * g2;
        Vt = u24 + spk_t * 0.0f;                 FPBAR(Vt);
        spk_prev = spk_t;

        p0[0] = spk_l;
        p1[0] = spk_t;
        p0 += step;
        p1 += step;
    }
}

extern "C" void kernel_launch(void* const* d_in, const int* in_sizes, int n_in,
                              void* d_out, int out_size, void* d_ws, size_t ws_size,
                              hipStream_t stream) {
    const float* a0 = (const float*)d_in[0];
    const float* a1 = (const float*)d_in[1];
    const float* inp = a0;
    const float* cur = a1;
    if (n_in >= 2 && in_sizes[0] == N && in_sizes[1] == T * BS) { inp = a1; cur = a0; }
    float* out = (float*)d_out;
    spll_kernel<<<dim3(BS), dim3(N), 0, stream>>>(inp, cur, out);
}

// Round 12
// 64.232 us; speedup vs baseline: 1.5723x; 1.5723x over previous
//
#include <hip/hip_runtime.h>

// sPLL — verified bit-exact arithmetic (R11 PASS), now optimized:
//   * t-loop manually unrolled x4 (500 = 4*125) with DISTINCT spike
//     registers per unrolled step; stores batched at group end
//     => store-ack latency (~200-400cy) hides behind ~4 dependency chains
//     instead of stalling every iteration on VGPR-reuse vmcnt waits.
//   * input spike train read as one ds_read_b128 (float4) per group.
// Arithmetic is IDENTICAL to the passing kernel (recip-mul *100.0f /
// *999.99993896484375f, second-operand-FMA drive, FMA V-accumulate,
// unfused Il/itrg leak updates, barriered).
static constexpr int T  = 500;
static constexpr int BS = 256;
static constexpr int N  = 256;
static constexpr int U  = 4;          // unroll factor (T % U == 0)

#define FPBAR(x) asm("" : "+v"(x))

__device__ __forceinline__ void do_step(
    float x, float steady,
    float& Vl, float& Il, float& crl,
    float& Vt, float& itrg, float& ifac, float& crt,
    float& spk_prev, float& sl_out, float& st_out)
{
    const float RC = 999.99993896484375f;   // f32(1/f32(0.001))

    // ---- LIF ----
    float u0 = Il * 0.8f;                    FPBAR(u0);
    float u1 = 1e-3f * spk_prev;             FPBAR(u1);   // exact
    Il = u0 + u1;                            FPBAR(Il);
    float u2 = -Vl;                          FPBAR(u2);
    float u3 = u2 * 100.0f;                  FPBAR(u3);
    float u4 = Il + steady;                  FPBAR(u4);
    float u6 = __builtin_fmaf(u4, RC, u3);   FPBAR(u6);
    Vl = __builtin_fmaf(1e-3f, u6, Vl);      FPBAR(Vl);
    float dvl = Vl - 1.0f;                   FPBAR(dvl);
    float spk_l = (dvl > 0.0f) ? 1.0f : 0.0f;
    float ns = 1.0f - spk_l;                             // exact
    float u8 = crl - 1.0f;                               // exact
    crl = 2.0f * spk_l + ns * u8;            FPBAR(crl); // exact
    float g1 = (crl <= 0.0f) ? 1.0f : 0.0f;
    float u9  = ns * Vl;                                 // exact select
    float u10 = u9 * g1;                                 // exact select
    Vl = u10 + spk_l * 0.0f;                 FPBAR(Vl);

    // ---- TDE ----
    float u11 = ifac * ns;                               // exact select
    float u12 = spk_l * 1.0f;                            // exact
    float u13 = u12 + u11;                   FPBAR(u13); // exact
    ifac = u13 * 0.8f;                       FPBAR(ifac);
    float w0 = itrg * 0.9f;                  FPBAR(w0);
    float m1 = (ifac > 0.1f) ? 1.0f : 0.0f;
    float u14 = x * 2.0f;                                // exact
    float u15 = u14 * ifac;                  FPBAR(u15);
    float u16 = u15 * m1;                                // exact select
    itrg = w0 + u16;                         FPBAR(itrg);
    float u17 = -Vt;                         FPBAR(u17);
    float u18 = u17 * 100.0f;                FPBAR(u18);
    float u20 = __builtin_fmaf(itrg, RC, u18); FPBAR(u20);
    Vt = __builtin_fmaf(1e-3f, u20, Vt);     FPBAR(Vt);
    float dvt = Vt - 1.0f;                   FPBAR(dvt);
    float spk_t = (dvt > 0.0f) ? 1.0f : 0.0f;
    float nst = 1.0f - spk_t;
    float u22 = crt - 1.0f;
    crt = 2.0f * spk_t + nst * u22;          FPBAR(crt);
    float g2 = (crt <= 0.0f) ? 1.0f : 0.0f;
    float u23 = nst * Vt;
    float u24 = u23 * g2;
    Vt = u24 + spk_t * 0.0f;                 FPBAR(Vt);
    spk_prev = spk_t;

    sl_out = spk_l;
    st_out = spk_t;
}

__global__ __launch_bounds__(256, 1) void spll_kernel(
    const float* __restrict__ inp,      // (T, BS)
    const float* __restrict__ current,  // (N,)
    float* __restrict__ out)            // (2, T, BS, N)
{
#pragma clang fp contract(off)
    const int b = blockIdx.x;
    const int n = threadIdx.x;

    __shared__ __align__(16) float s_inp[T];
    for (int i = threadIdx.x; i < T; i += blockDim.x)
        s_inp[i] = inp[i * BS + b];
    __syncthreads();

    const float steady = current[n];

    float Vl = 1.0f, Il = 0.0f, crl = 0.0f;
    float Vt = 0.0f, itrg = 0.0f, ifac = 0.0f, crt = 0.0f;
    float spk_prev = 0.0f;

    float* p0 = out + (size_t)b * N + n;
    float* p1 = p0 + (size_t)T * BS * N;
    const size_t step = (size_t)BS * N;

    for (int g = 0; g < T / U; ++g) {
        const float4 xv = *reinterpret_cast<const float4*>(&s_inp[g * U]);

        float sl0, st0, sl1, st1, sl2, st2, sl3, st3;
        do_step(xv.x, steady, Vl, Il, crl, Vt, itrg, ifac, crt, spk_prev, sl0, st0);
        do_step(xv.y, steady, Vl, Il, crl, Vt, itrg, ifac, crt, spk_prev, sl1, st1);
        do_step(xv.z, steady, Vl, Il, crl, Vt, itrg, ifac, crt, spk_prev, sl2, st2);
        do_step(xv.w, steady, Vl, Il, crl, Vt, itrg, ifac, crt, spk_prev, sl3, st3);

        p0[0]        = sl0;
        p0[step]     = sl1;
        p0[2 * step] = sl2;
        p0[3 * step] = sl3;
        p1[0]        = st0;
        p1[step]     = st1;
        p1[2 * step] = st2;
        p1[3 * step] = st3;
        p0 += (size_t)U * step;
        p1 += (size_t)U * step;
    }
}

extern "C" void kernel_launch(void* const* d_in, const int* in_sizes, int n_in,
                              void* d_out, int out_size, void* d_ws, size_t ws_size,
                              hipStream_t stream) {
    const float* a0 = (const float*)d_in[0];
    const float* a1 = (const float*)d_in[1];
    const float* inp = a0;
    const float* cur = a1;
    if (n_in >= 2 && in_sizes[0] == N && in_sizes[1] == T * BS) { inp = a1; cur = a0; }
    float* out = (float*)d_out;
    spll_kernel<<<dim3(BS), dim3(N), 0, stream>>>(inp, cur, out);
}

// Round 13
// 61.746 us; speedup vs baseline: 1.6356x; 1.0403x over previous
//
#include <hip/hip_runtime.h>

// sPLL — bit-exact arithmetic (verified R11/R12), scheduling-only change:
//   * unroll U=10 (500 = 10*50): register-reuse distance ~10 dep chains
//     (~600 cyc) > global write-ack latency => no vmcnt stalls
//   * stores issued immediately after each step (earliest issue)
//   * LDS input read as float2 x5 per group (8B-aligned, 40B stride)
// do_step is BYTE-IDENTICAL to the passing R12 kernel.
static constexpr int T  = 500;
static constexpr int BS = 256;
static constexpr int N  = 256;
static constexpr int U  = 10;         // unroll factor (T % U == 0)

#define FPBAR(x) asm("" : "+v"(x))

__device__ __forceinline__ void do_step(
    float x, float steady,
    float& Vl, float& Il, float& crl,
    float& Vt, float& itrg, float& ifac, float& crt,
    float& spk_prev, float& sl_out, float& st_out)
{
    const float RC = 999.99993896484375f;   // f32(1/f32(0.001))

    // ---- LIF ----
    float u0 = Il * 0.8f;                    FPBAR(u0);
    float u1 = 1e-3f * spk_prev;             FPBAR(u1);   // exact
    Il = u0 + u1;                            FPBAR(Il);
    float u2 = -Vl;                          FPBAR(u2);
    float u3 = u2 * 100.0f;                  FPBAR(u3);
    float u4 = Il + steady;                  FPBAR(u4);
    float u6 = __builtin_fmaf(u4, RC, u3);   FPBAR(u6);
    Vl = __builtin_fmaf(1e-3f, u6, Vl);      FPBAR(Vl);
    float dvl = Vl - 1.0f;                   FPBAR(dvl);
    float spk_l = (dvl > 0.0f) ? 1.0f : 0.0f;
    float ns = 1.0f - spk_l;                             // exact
    float u8 = crl - 1.0f;                               // exact
    crl = 2.0f * spk_l + ns * u8;            FPBAR(crl); // exact
    float g1 = (crl <= 0.0f) ? 1.0f : 0.0f;
    float u9  = ns * Vl;                                 // exact select
    float u10 = u9 * g1;                                 // exact select
    Vl = u10 + spk_l * 0.0f;                 FPBAR(Vl);

    // ---- TDE ----
    float u11 = ifac * ns;                               // exact select
    float u12 = spk_l * 1.0f;                            // exact
    float u13 = u12 + u11;                   FPBAR(u13); // exact
    ifac = u13 * 0.8f;                       FPBAR(ifac);
    float w0 = itrg * 0.9f;                  FPBAR(w0);
    float m1 = (ifac > 0.1f) ? 1.0f : 0.0f;
    float u14 = x * 2.0f;                                // exact
    float u15 = u14 * ifac;                  FPBAR(u15);
    float u16 = u15 * m1;                                // exact select
    itrg = w0 + u16;                         FPBAR(itrg);
    float u17 = -Vt;                         FPBAR(u17);
    float u18 = u17 * 100.0f;                FPBAR(u18);
    float u20 = __builtin_fmaf(itrg, RC, u18); FPBAR(u20);
    Vt = __builtin_fmaf(1e-3f, u20, Vt);     FPBAR(Vt);
    float dvt = Vt - 1.0f;                   FPBAR(dvt);
    float spk_t = (dvt > 0.0f) ? 1.0f : 0.0f;
    float nst = 1.0f - spk_t;
    float u22 = crt - 1.0f;
    crt = 2.0f * spk_t + nst * u22;          FPBAR(crt);
    float g2 = (crt <= 0.0f) ? 1.0f : 0.0f;
    float u23 = nst * Vt;
    float u24 = u23 * g2;
    Vt = u24 + spk_t * 0.0f;                 FPBAR(Vt);
    spk_prev = spk_t;

    sl_out = spk_l;
    st_out = spk_t;
}

__global__ __launch_bounds__(256, 1) void spll_kernel(
    const float* __restrict__ inp,      // (T, BS)
    const float* __restrict__ current,  // (N,)
    float* __restrict__ out)            // (2, T, BS, N)
{
#pragma clang fp contract(off)
    const int b = blockIdx.x;
    const int n = threadIdx.x;

    __shared__ __align__(16) float s_inp[T];
    for (int i = threadIdx.x; i < T; i += blockDim.x)
        s_inp[i] = inp[i * BS + b];
    __syncthreads();

    const float steady = current[n];

    float Vl = 1.0f, Il = 0.0f, crl = 0.0f;
    float Vt = 0.0f, itrg = 0.0f, ifac = 0.0f, crt = 0.0f;
    float spk_prev = 0.0f;

    float* p0 = out + (size_t)b * N + n;
    float* p1 = p0 + (size_t)T * BS * N;
    const size_t step = (size_t)BS * N;   // 65536

    for (int g = 0; g < T / U; ++g) {
        // 5 x float2 loads (40B stride, 8B-aligned)
        const float2 x01 = *reinterpret_cast<const float2*>(&s_inp[g * U + 0]);
        const float2 x23 = *reinterpret_cast<const float2*>(&s_inp[g * U + 2]);
        const float2 x45 = *reinterpret_cast<const float2*>(&s_inp[g * U + 4]);
        const float2 x67 = *reinterpret_cast<const float2*>(&s_inp[g * U + 6]);
        const float2 x89 = *reinterpret_cast<const float2*>(&s_inp[g * U + 8]);

        float sl, st;
        do_step(x01.x, steady, Vl, Il, crl, Vt, itrg, ifac, crt, spk_prev, sl, st);
        p0[0 * step] = sl;  p1[0 * step] = st;
        do_step(x01.y, steady, Vl, Il, crl, Vt, itrg, ifac, crt, spk_prev, sl, st);
        p0[1 * step] = sl;  p1[1 * step] = st;
        do_step(x23.x, steady, Vl, Il, crl, Vt, itrg, ifac, crt, spk_prev, sl, st);
        p0[2 * step] = sl;  p1[2 * step] = st;
        do_step(x23.y, steady, Vl, Il, crl, Vt, itrg, ifac, crt, spk_prev, sl, st);
        p0[3 * step] = sl;  p1[3 * step] = st;
        do_step(x45.x, steady, Vl, Il, crl, Vt, itrg, ifac, crt, spk_prev, sl, st);
        p0[4 * step] = sl;  p1[4 * step] = st;
        do_step(x45.y, steady, Vl, Il, crl, Vt, itrg, ifac, crt, spk_prev, sl, st);
        p0[5 * step] = sl;  p1[5 * step] = st;
        do_step(x67.x, steady, Vl, Il, crl, Vt, itrg, ifac, crt, spk_prev, sl, st);
        p0[6 * step] = sl;  p1[6 * step] = st;
        do_step(x67.y, steady, Vl, Il, crl, Vt, itrg, ifac, crt, spk_prev, sl, st);
        p0[7 * step] = sl;  p1[7 * step] = st;
        do_step(x89.x, steady, Vl, Il, crl, Vt, itrg, ifac, crt, spk_prev, sl, st);
        p0[8 * step] = sl;  p1[8 * step] = st;
        do_step(x89.y, steady, Vl, Il, crl, Vt, itrg, ifac, crt, spk_prev, sl, st);
        p0[9 * step] = sl;  p1[9 * step] = st;

        p0 += (size_t)U * step;
        p1 += (size_t)U * step;
    }
}

extern "C" void kernel_launch(void* const* d_in, const int* in_sizes, int n_in,
                              void* d_out, int out_size, void* d_ws, size_t ws_size,
                              hipStream_t stream) {
    const float* a0 = (const float*)d_in[0];
    const float* a1 = (const float*)d_in[1];
    const float* inp = a0;
    const float* cur = a1;
    if (n_in >= 2 && in_sizes[0] == N && in_sizes[1] == T * BS) { inp = a1; cur = a0; }
    float* out = (float*)d_out;
    spll_kernel<<<dim3(BS), dim3(N), 0, stream>>>(inp, cur, out);
}

// Round 14
// 54.980 us; speedup vs baseline: 1.8368x; 1.1231x over previous
//
#include <hip/hip_runtime.h>

// sPLL — bit-exact arithmetic (verified R11-R13). This round:
//  1) exact {0,1}-mask algebra rewritten as cndmask selects (verified
//     bit-identical incl. signed-zero paths); rounded ops unchanged+FPBAR.
//  2) time-split redundancy: 512 blocks; role A (blk<256) simulates
//     t=[0,380) and stores; role B simulates t=[0,500) (recomputing the
//     prefix) and stores t=[380,500). Same recurrence, same init => same
//     bits; but now 2 waves/SIMD so chain bubbles are filled.
static constexpr int T     = 500;
static constexpr int BS    = 256;
static constexpr int N     = 256;
static constexpr int U     = 10;     // unroll (SPLIT and T multiples of U)
static constexpr int SPLIT = 380;    // A stores [0,SPLIT), B stores [SPLIT,T)

#define FPBAR(x) asm("" : "+v"(x))

__device__ __forceinline__ void do_step(
    float x, float steady,
    float& Vl, float& Il, float& crl,
    float& Vt, float& itrg, float& ifac, float& crt,
    bool& sp_b, float& sl_out, float& st_out)
{
    const float RC = 999.99993896484375f;   // f32(1/f32(0.001))

    // ---- LIF ----
    float u0 = Il * 0.8f;                     FPBAR(u0);
    float u1 = sp_b ? 1e-3f : 0.0f;                       // == 1e-3f*spk
    Il = u0 + u1;                             FPBAR(Il);
    float u3 = -Vl * 100.0f;                  FPBAR(u3);  // == (-Vl)*100
    float u4 = Il + steady;                   FPBAR(u4);
    float u6 = __builtin_fmaf(u4, RC, u3);    FPBAR(u6);
    Vl = __builtin_fmaf(1e-3f, u6, Vl);       FPBAR(Vl);
    float dvl = Vl - 1.0f;                    FPBAR(dvl);
    bool  bl  = dvl > 0.0f;
    float crm = crl - 1.0f;                               // exact small ints
    bool  rg  = crm <= 0.0f;                              // == (crl'<=0) when !bl
    crl = bl ? 2.0f : crm;                                // == 2*spk+ns*(crl-1)
    Vl  = bl ? 0.0f : (rg ? Vl : 0.0f);                   // == ns*Vl*g1+spk*0 (+0 paths verified)
    sl_out = bl ? 1.0f : 0.0f;

    // ---- TDE ----
    float u13 = bl ? 1.0f : ifac;                         // == spk + ifac*ns
    ifac = u13 * 0.8f;                        FPBAR(ifac);
    float w0 = itrg * 0.9f;                   FPBAR(w0);
    float df  = ifac + ifac;                              // exact 2x
    float dfx = x * df;                       FPBAR(dfx); // exact (x in {0,1})
    bool  m1  = ifac > 0.1f;
    float pulse = m1 ? dfx : 0.0f;                        // == (x*2)*ifac*m1
    itrg = w0 + pulse;                        FPBAR(itrg);
    float u18 = -Vt * 100.0f;                 FPBAR(u18);
    float u20 = __builtin_fmaf(itrg, RC, u18); FPBAR(u20);
    Vt = __builtin_fmaf(1e-3f, u20, Vt);      FPBAR(Vt);
    float dvt = Vt - 1.0f;                    FPBAR(dvt);
    bool  bt  = dvt > 0.0f;
    float ctm = crt - 1.0f;
    bool  rg2 = ctm <= 0.0f;
    crt = bt ? 2.0f : ctm;
    Vt  = bt ? 0.0f : (rg2 ? Vt : 0.0f);
    st_out = bt ? 1.0f : 0.0f;
    sp_b = bt;
}

struct Cell {
    float Vl, Il, crl, Vt, itrg, ifac, crt;
    bool  sp;
};

template <bool STORE>
__device__ __forceinline__ void run_group(
    const float* __restrict__ s_inp, int g, float steady, Cell& c,
    float*& p0, float*& p1, size_t step)
{
    const float2 x01 = *reinterpret_cast<const float2*>(&s_inp[g * U + 0]);
    const float2 x23 = *reinterpret_cast<const float2*>(&s_inp[g * U + 2]);
    const float2 x45 = *reinterpret_cast<const float2*>(&s_inp[g * U + 4]);
    const float2 x67 = *reinterpret_cast<const float2*>(&s_inp[g * U + 6]);
    const float2 x89 = *reinterpret_cast<const float2*>(&s_inp[g * U + 8]);
    const float xs[U] = {x01.x, x01.y, x23.x, x23.y, x45.x,
                         x45.y, x67.x, x67.y, x89.x, x89.y};
    float sl, st;
#pragma unroll
    for (int j = 0; j < U; ++j) {
        do_step(xs[j], steady, c.Vl, c.Il, c.crl, c.Vt, c.itrg, c.ifac, c.crt,
                c.sp, sl, st);
        if (STORE) {
            p0[(size_t)j * step] = sl;
            p1[(size_t)j * step] = st;
        }
    }
    if (STORE) {
        p0 += (size_t)U * step;
        p1 += (size_t)U * step;
    }
}

__global__ __launch_bounds__(256, 2) void spll_kernel(
    const float* __restrict__ inp,      // (T, BS)
    const float* __restrict__ current,  // (N,)
    float* __restrict__ out)            // (2, T, BS, N)
{
#pragma clang fp contract(off)
    const int b    = blockIdx.x & (BS - 1);
    const int role = blockIdx.x >> 8;       // 0: t=[0,SPLIT) ; 1: stores [SPLIT,T)
    const int n    = threadIdx.x;

    __shared__ __align__(16) float s_inp[T];
    for (int i = threadIdx.x; i < T; i += blockDim.x)
        s_inp[i] = inp[i * BS + b];
    __syncthreads();

    const float steady = current[n];

    Cell c = {1.0f, 0.0f, 0.0f, 0.0f, 0.0f, 0.0f, 0.0f, false};

    float* p0 = out + (size_t)b * N + n;
    float* p1 = p0 + (size_t)T * BS * N;
    const size_t step = (size_t)BS * N;   // 65536

    if (role == 0) {
        for (int g = 0; g < SPLIT / U; ++g)
            run_group<true>(s_inp, g, steady, c, p0, p1, step);
    } else {
        // skip stores for the recomputed prefix, then store the tail
        p0 += (size_t)SPLIT * step;
        p1 += (size_t)SPLIT * step;
        for (int g = 0; g < SPLIT / U; ++g)
            run_group<false>(s_inp, g, steady, c, p0, p1, step);
        for (int g = SPLIT / U; g < T / U; ++g)
            run_group<true>(s_inp, g, steady, c, p0, p1, step);
    }
}

extern "C" void kernel_launch(void* const* d_in, const int* in_sizes, int n_in,
                              void* d_out, int out_size, void* d_ws, size_t ws_size,
                              hipStream_t stream) {
    const float* a0 = (const float*)d_in[0];
    const float* a1 = (const float*)d_in[1];
    const float* inp = a0;
    const float* cur = a1;
    if (n_in >= 2 && in_sizes[0] == N && in_sizes[1] == T * BS) { inp = a1; cur = a0; }
    float* out = (float*)d_out;
    spll_kernel<<<dim3(2 * BS), dim3(N), 0, stream>>>(inp, cur, out);
}